// Round 1
// baseline (420.688 us; speedup 1.0000x reference)
//
#include <hip/hip_runtime.h>

typedef unsigned short u16;
typedef __bf16 bf16x8 __attribute__((ext_vector_type(8)));
typedef float f32x4 __attribute__((ext_vector_type(4)));
typedef unsigned short u16x4 __attribute__((ext_vector_type(4)));

typedef __attribute__((address_space(1))) const unsigned int* gas_t;
typedef __attribute__((address_space(3))) unsigned int* las_t;

__device__ __forceinline__ void gload16(const void* gsrc, void* ldst) {
  __builtin_amdgcn_global_load_lds((gas_t)gsrc, (las_t)ldst, 16, 0, 0);
}

__device__ __forceinline__ u16 f2bf(float f) {
  unsigned u = __builtin_bit_cast(unsigned, f);
  unsigned r = u + 0x7fffu + ((u >> 16) & 1u);
  return (u16)(r >> 16);
}
__device__ __forceinline__ float bf2f(u16 h) {
  unsigned u = ((unsigned)h) << 16;
  return __builtin_bit_cast(float, u);
}

// ---------------- x -> bf16 ----------------
__global__ __launch_bounds__(256) void cvt_x(const float* __restrict__ x, u16* __restrict__ xb) {
  int i = blockIdx.x * 256 + threadIdx.x;
  f32x4 v = ((const f32x4*)x)[i];
  u16x4 o = { f2bf(v[0]), f2bf(v[1]), f2bf(v[2]), f2bf(v[3]) };
  ((u16x4*)xb)[i] = o;
}

// ------------- transpose + convert weights: in [K][N] f32 -> out [N][K] bf16 -------------
__global__ __launch_bounds__(256) void transpose_cvt(const float* __restrict__ in, u16* __restrict__ out,
                                                     int K, int N) {
  __shared__ float tile[32][33];
  int n0 = blockIdx.x * 32, k0 = blockIdx.y * 32;
  int tx = threadIdx.x, ty = threadIdx.y; // 32 x 8
#pragma unroll
  for (int i = 0; i < 4; ++i)
    tile[ty + i * 8][tx] = in[(size_t)(k0 + ty + i * 8) * N + n0 + tx];
  __syncthreads();
#pragma unroll
  for (int i = 0; i < 4; ++i)
    out[(size_t)(n0 + ty + i * 8) * K + k0 + tx] = f2bf(tile[tx][ty + i * 8]);
}

// ------------- GEMM: A [M][K] bf16, Bt [N][K] bf16 -> C [M][N] (bf16 or f32) -------------
// m97 structure: 128x128 tile, BK=32, 4 waves (2x2 of 64x64), global_load_lds width-16 staging.
template <int OUTBF>
__global__ __launch_bounds__(256) void gemm_bt(const u16* __restrict__ A, const u16* __restrict__ Bt,
                                               void* __restrict__ Cout, int M, int N, int K) {
  __shared__ u16 As[128 * 32];
  __shared__ u16 Bs[128 * 32];
  const int tid = threadIdx.x;
  const int w = tid >> 6, l = tid & 63, lg = l >> 4, lr = l & 15;
  const int m0 = blockIdx.y * 128, n0 = blockIdx.x * 128;
  const int wr = w >> 1, wc = w & 1;
  f32x4 acc[4][4];
#pragma unroll
  for (int m = 0; m < 4; ++m)
#pragma unroll
    for (int n = 0; n < 4; ++n) acc[m][n] = (f32x4){0.f, 0.f, 0.f, 0.f};

  for (int k0 = 0; k0 < K; k0 += 32) {
    __syncthreads();
#pragma unroll
    for (int j = 0; j < 2; ++j) {
      int c = w * 64 + j * 256 + l;   // chunk id 0..511, 16B each
      int row = c >> 2, kb = c & 3;   // 4 chunks (32 bf16) per row
      gload16(A + (size_t)(m0 + row) * K + k0 + kb * 8, &As[(w * 64 + j * 256) * 8]);
      gload16(Bt + (size_t)(n0 + row) * K + k0 + kb * 8, &Bs[(w * 64 + j * 256) * 8]);
    }
    __syncthreads();
    bf16x8 af[4], bf[4];
#pragma unroll
    for (int m = 0; m < 4; ++m)
      af[m] = *(const bf16x8*)&As[(wr * 64 + m * 16 + lr) * 32 + lg * 8];
#pragma unroll
    for (int n = 0; n < 4; ++n)
      bf[n] = *(const bf16x8*)&Bs[(wc * 64 + n * 16 + lr) * 32 + lg * 8];
#pragma unroll
    for (int m = 0; m < 4; ++m)
#pragma unroll
      for (int n = 0; n < 4; ++n)
        acc[m][n] = __builtin_amdgcn_mfma_f32_16x16x32_bf16(af[m], bf[n], acc[m][n], 0, 0, 0);
  }
#pragma unroll
  for (int m = 0; m < 4; ++m)
#pragma unroll
    for (int n = 0; n < 4; ++n)
#pragma unroll
      for (int r = 0; r < 4; ++r) {
        int row = m0 + wr * 64 + m * 16 + lg * 4 + r;
        int col = n0 + wc * 64 + n * 16 + lr;
        float v = acc[m][n][r];
        if (OUTBF)
          ((u16*)Cout)[(size_t)row * N + col] = f2bf(v);
        else
          ((float*)Cout)[(size_t)row * N + col] = v;
      }
}

// ------------- RoPE: qkv [4096][3072] bf16 -> dst [B][nh][S][64] bf16 -------------
__global__ __launch_bounds__(256) void rope_kernel(const u16* __restrict__ qkv, const float* __restrict__ fcos,
                                                   const float* __restrict__ fsin, u16* __restrict__ dst,
                                                   int nhs /*log2 nheads*/, int col0) {
  int idx = blockIdx.x * 256 + threadIdx.x;
  int p = idx & 31;
  int h = (idx >> 5) & ((1 << nhs) - 1);
  int t = idx >> (5 + nhs);
  int s = t & 2047, b = t >> 11;
  unsigned v = *(const unsigned*)(qkv + (size_t)t * 3072 + col0 + h * 64 + 2 * p);
  float xr = bf2f((u16)(v & 0xffff)), xi = bf2f((u16)(v >> 16));
  float c = fcos[s * 32 + p], sn = fsin[s * 32 + p];
  float orr = xr * c - xi * sn;
  float oii = xr * sn + xi * c;
  unsigned o = (unsigned)f2bf(orr) | ((unsigned)f2bf(oii) << 16);
  *(unsigned*)(dst + (((size_t)((b << nhs) + h) * 2048 + s) * 64 + 2 * p)) = o;
}

// ------------- V transpose: qkv cols [2560..3072) -> vT [(b*8+kv)*64+d][S] -------------
__global__ __launch_bounds__(256) void vtrans(const u16* __restrict__ qkv, u16* __restrict__ vT) {
  __shared__ u16 tile[32][33];
  int c0 = blockIdx.x * 32, t0 = blockIdx.y * 32;
  int tx = threadIdx.x, ty = threadIdx.y;
#pragma unroll
  for (int i = 0; i < 4; ++i)
    tile[ty + i * 8][tx] = qkv[(size_t)(t0 + ty + i * 8) * 3072 + 2560 + c0 + tx];
  __syncthreads();
#pragma unroll
  for (int i = 0; i < 4; ++i) {
    int c = c0 + ty + i * 8;
    int tok = t0 + tx;
    vT[((size_t)((tok >> 11) * 8 + (c >> 6)) * 64 + (c & 63)) * 2048 + (tok & 2047)] = tile[tx][ty + i * 8];
  }
}

// ------------- Flash attention: Q [B*H][S][64], K [B*KV][S][64], Vt [B*KV][64][S] -------------
// 4 waves/block, each wave: 16 q rows. 64-key tiles, online softmax, XOR-swizzled LDS.
__global__ __launch_bounds__(256) void attn(const u16* __restrict__ Q, const u16* __restrict__ Kb,
                                            const u16* __restrict__ Vt, const float* __restrict__ mask,
                                            u16* __restrict__ Ao) {
  __shared__ u16 Ks[64 * 64];
  __shared__ u16 Vs[64 * 64];
  __shared__ u16 Ps[4 * 16 * 64];
  const int bid = blockIdx.x;
  const int qt = bid & 31, h = (bid >> 5) & 31, b = bid >> 10;
  const int kv = h >> 2;
  const int tid = threadIdx.x, w = tid >> 6, l = tid & 63, lg = l >> 4, lr = l & 15;

  const u16* Qb = Q + ((size_t)((b * 32 + h) * 2048 + qt * 64 + w * 16)) * 64;
  bf16x8 qf[2];
#pragma unroll
  for (int t = 0; t < 2; ++t)
    qf[t] = *(const bf16x8*)(Qb + (size_t)lr * 64 + t * 32 + lg * 8);

  const u16* Ksrc = Kb + (size_t)(b * 8 + kv) * 2048 * 64;
  const u16* Vsrc = Vt + (size_t)(b * 8 + kv) * 64 * 2048;
  const float* Mrow = mask + (size_t)(qt * 64) * 2048;
  u16* Pw = Ps + w * 1024;

  float mrun[4], lrun[4];
  f32x4 o[4];
#pragma unroll
  for (int r = 0; r < 4; ++r) { mrun[r] = -3.0e38f; lrun[r] = 0.f; }
#pragma unroll
  for (int dc = 0; dc < 4; ++dc) o[dc] = (f32x4){0.f, 0.f, 0.f, 0.f};

  const float SCL = 0.125f;
  const float L2E = 1.44269504088896f;

  for (int kt = 0; kt < 32; ++kt) {
    const int k0 = kt * 64;
    __syncthreads();
    // stage K tile [64 keys][64 d] and V^T tile [64 d][64 s], XOR-swizzled (blk ^= row&7)
#pragma unroll
    for (int j = 0; j < 2; ++j) {
      int c = w * 64 + j * 256 + l;
      int row = c >> 3, xb8 = c & 7;
      gload16(Ksrc + (size_t)(k0 + row) * 64 + (xb8 ^ (row & 7)) * 8, &Ks[(w * 64 + j * 256) * 8]);
      gload16(Vsrc + (size_t)row * 2048 + k0 + (xb8 ^ (row & 7)) * 8, &Vs[(w * 64 + j * 256) * 8]);
    }
    __syncthreads();

    // QK^T (+ scale + mask from global, L2-hot)
    float sc[4][4];
#pragma unroll
    for (int cc = 0; cc < 4; ++cc) {
      f32x4 a = (f32x4){0.f, 0.f, 0.f, 0.f};
      int kcol = cc * 16 + lr;
#pragma unroll
      for (int t = 0; t < 2; ++t) {
        int byteoff = kcol * 128 + ((t * 64 + lg * 16) ^ ((kcol & 7) << 4));
        bf16x8 bfr = *(const bf16x8*)((const char*)Ks + byteoff);
        a = __builtin_amdgcn_mfma_f32_16x16x32_bf16(qf[t], bfr, a, 0, 0, 0);
      }
#pragma unroll
      for (int r = 0; r < 4; ++r) {
        float mk = Mrow[(size_t)(w * 16 + lg * 4 + r) * 2048 + k0 + cc * 16 + lr];
        sc[cc][r] = a[r] * SCL + mk;
      }
    }

    // online softmax (per row; rows live in 16-lane groups -> width-16 shuffles)
    float tmx[4];
#pragma unroll
    for (int r = 0; r < 4; ++r)
      tmx[r] = fmaxf(fmaxf(sc[0][r], sc[1][r]), fmaxf(sc[2][r], sc[3][r]));
#pragma unroll
    for (int s = 1; s < 16; s <<= 1)
#pragma unroll
      for (int r = 0; r < 4; ++r) tmx[r] = fmaxf(tmx[r], __shfl_xor(tmx[r], s, 16));

    float mnew[4], corr[4];
#pragma unroll
    for (int r = 0; r < 4; ++r) {
      mnew[r] = fmaxf(mrun[r], tmx[r]);
      corr[r] = exp2f((mrun[r] - mnew[r]) * L2E);
      mrun[r] = mnew[r];
    }
    float p[4][4], rsum[4];
#pragma unroll
    for (int cc = 0; cc < 4; ++cc)
#pragma unroll
      for (int r = 0; r < 4; ++r) p[cc][r] = exp2f((sc[cc][r] - mnew[r]) * L2E);
#pragma unroll
    for (int r = 0; r < 4; ++r) rsum[r] = p[0][r] + p[1][r] + p[2][r] + p[3][r];
#pragma unroll
    for (int s = 1; s < 16; s <<= 1)
#pragma unroll
      for (int r = 0; r < 4; ++r) rsum[r] += __shfl_xor(rsum[r], s, 16);
#pragma unroll
    for (int r = 0; r < 4; ++r) lrun[r] = lrun[r] * corr[r] + rsum[r];
#pragma unroll
    for (int dc = 0; dc < 4; ++dc)
#pragma unroll
      for (int r = 0; r < 4; ++r) o[dc][r] *= corr[r];

    // P -> LDS (bf16, swizzled), then PV
#pragma unroll
    for (int cc = 0; cc < 4; ++cc)
#pragma unroll
      for (int r = 0; r < 4; ++r) {
        int row = lg * 4 + r;
        int colb = (cc * 16 + lr) * 2;
        *(u16*)((char*)Pw + row * 128 + (colb ^ ((row & 7) << 4))) = f2bf(p[cc][r]);
      }
    bf16x8 pa[2];
#pragma unroll
    for (int t = 0; t < 2; ++t)
      pa[t] = *(const bf16x8*)((const char*)Pw + lr * 128 + ((t * 64 + lg * 16) ^ ((lr & 7) << 4)));
#pragma unroll
    for (int dc = 0; dc < 4; ++dc) {
      int vrow = dc * 16 + lr;
#pragma unroll
      for (int t = 0; t < 2; ++t) {
        bf16x8 vb = *(const bf16x8*)((const char*)Vs + vrow * 128 + ((t * 64 + lg * 16) ^ ((vrow & 7) << 4)));
        o[dc] = __builtin_amdgcn_mfma_f32_16x16x32_bf16(pa[t], vb, o[dc], 0, 0, 0);
      }
    }
  }

  // epilogue: normalize and store attn_out [token][h*64+d] bf16
#pragma unroll
  for (int r = 0; r < 4; ++r) {
    float inv = 1.0f / lrun[r];
#pragma unroll
    for (int dc = 0; dc < 4; ++dc) {
      int tok = b * 2048 + qt * 64 + w * 16 + lg * 4 + r;
      int col = h * 64 + dc * 16 + lr;
      Ao[(size_t)tok * 2048 + col] = f2bf(o[dc][r] * inv);
    }
  }
}

extern "C" void kernel_launch(void* const* d_in, const int* in_sizes, int n_in,
                              void* d_out, int out_size, void* d_ws, size_t ws_size,
                              hipStream_t stream) {
  const float* x    = (const float*)d_in[0];
  const float* fcos = (const float*)d_in[1];
  const float* fsin = (const float*)d_in[2];
  const float* mask = (const float*)d_in[3];
  const float* wq   = (const float*)d_in[4];
  const float* wk   = (const float*)d_in[5];
  const float* wv   = (const float*)d_in[6];
  const float* wo   = (const float*)d_in[7];
  float* out = (float*)d_out;

  // workspace layout (u16 elements), total 39,845,888 u16 = ~79.7 MB
  u16* ws  = (u16*)d_ws;
  u16* xb  = ws;                       // 8,388,608   x bf16; later reused as attn_out
  u16* wT  = ws + 8388608;             // 6,291,456   wqkvT [3072][2048]; later woT [2048][2048]
  u16* qkv = ws + 14680064;            // 12,582,912  qkv [4096][3072]
  u16* qb  = ws + 27262976;            // 8,388,608   Q [B][32][S][64]
  u16* kb  = ws + 35651584;            // 2,097,152   K [B][8][S][64]
  u16* vT  = ws + 37748736;            // 2,097,152   V^T [B*8][64][S]

  cvt_x<<<8192, 256, 0, stream>>>(x, xb);
  transpose_cvt<<<dim3(64, 64), dim3(32, 8), 0, stream>>>(wq, wT, 2048, 2048);
  transpose_cvt<<<dim3(16, 64), dim3(32, 8), 0, stream>>>(wk, wT + (size_t)2048 * 2048, 2048, 512);
  transpose_cvt<<<dim3(16, 64), dim3(32, 8), 0, stream>>>(wv, wT + (size_t)2560 * 2048, 2048, 512);
  gemm_bt<1><<<dim3(24, 32), 256, 0, stream>>>(xb, wT, qkv, 4096, 3072, 2048);
  transpose_cvt<<<dim3(64, 64), dim3(32, 8), 0, stream>>>(wo, wT, 2048, 2048);  // after gemm1 (wT reuse)
  rope_kernel<<<16384, 256, 0, stream>>>(qkv, fcos, fsin, qb, 5, 0);
  rope_kernel<<<4096, 256, 0, stream>>>(qkv, fcos, fsin, kb, 3, 2048);
  vtrans<<<dim3(16, 128), dim3(32, 8), 0, stream>>>(qkv, vT);
  attn<<<2048, 256, 0, stream>>>(qb, kb, vT, mask, xb);
  gemm_bt<0><<<dim3(16, 32), 256, 0, stream>>>(xb, wT, out, 4096, 2048, 2048);
}

// Round 3
// 382.636 us; speedup vs baseline: 1.0994x; 1.0994x over previous
//
#include <hip/hip_runtime.h>

typedef unsigned short u16;
typedef __bf16 bf16x8 __attribute__((ext_vector_type(8)));
typedef float f32x4 __attribute__((ext_vector_type(4)));
typedef float f32x16 __attribute__((ext_vector_type(16)));
typedef unsigned short u16x4 __attribute__((ext_vector_type(4)));
typedef unsigned int u32x2 __attribute__((ext_vector_type(2)));
typedef unsigned int u32x4 __attribute__((ext_vector_type(4)));

typedef __attribute__((address_space(1))) const unsigned int* gas_t;
typedef __attribute__((address_space(3))) unsigned int* las_t;

__device__ __forceinline__ void gload16(const void* gsrc, void* ldst) {
  __builtin_amdgcn_global_load_lds((gas_t)gsrc, (las_t)ldst, 16, 0, 0);
}

__device__ __forceinline__ u16 f2bf(float f) {
  unsigned u = __builtin_bit_cast(unsigned, f);
  unsigned r = u + 0x7fffu + ((u >> 16) & 1u);
  return (u16)(r >> 16);
}
__device__ __forceinline__ float bf2f(u16 h) {
  unsigned u = ((unsigned)h) << 16;
  return __builtin_bit_cast(float, u);
}
__device__ __forceinline__ unsigned cvtpk(float lo, float hi) {
  unsigned r;
  asm("v_cvt_pk_bf16_f32 %0, %1, %2" : "=v"(r) : "v"(lo), "v"(hi));
  return r;
}

// ---------------- x -> bf16 ----------------
__global__ __launch_bounds__(256) void cvt_x(const float* __restrict__ x, u16* __restrict__ xb) {
  int i = blockIdx.x * 256 + threadIdx.x;
  f32x4 v = ((const f32x4*)x)[i];
  u16x4 o = { f2bf(v[0]), f2bf(v[1]), f2bf(v[2]), f2bf(v[3]) };
  ((u16x4*)xb)[i] = o;
}

// ------------- transpose + convert weights: in [K][N] f32 -> out [N][K] bf16 -------------
__global__ __launch_bounds__(256) void transpose_cvt(const float* __restrict__ in, u16* __restrict__ out,
                                                     int K, int N) {
  __shared__ float tile[32][33];
  int n0 = blockIdx.x * 32, k0 = blockIdx.y * 32;
  int tx = threadIdx.x, ty = threadIdx.y; // 32 x 8
#pragma unroll
  for (int i = 0; i < 4; ++i)
    tile[ty + i * 8][tx] = in[(size_t)(k0 + ty + i * 8) * N + n0 + tx];
  __syncthreads();
#pragma unroll
  for (int i = 0; i < 4; ++i)
    out[(size_t)(n0 + ty + i * 8) * K + k0 + tx] = f2bf(tile[tx][ty + i * 8]);
}

// ------------- GEMM: A [M][K] bf16, Bt [N][K] bf16 -> C [M][N] (bf16 or f32) -------------
template <int OUTBF>
__global__ __launch_bounds__(256) void gemm_bt(const u16* __restrict__ A, const u16* __restrict__ Bt,
                                               void* __restrict__ Cout, int M, int N, int K) {
  __shared__ u16 As[128 * 32];
  __shared__ u16 Bs[128 * 32];
  const int tid = threadIdx.x;
  const int w = tid >> 6, l = tid & 63, lg = l >> 4, lr = l & 15;
  const int m0 = blockIdx.y * 128, n0 = blockIdx.x * 128;
  const int wr = w >> 1, wc = w & 1;
  f32x4 acc[4][4];
#pragma unroll
  for (int m = 0; m < 4; ++m)
#pragma unroll
    for (int n = 0; n < 4; ++n) acc[m][n] = (f32x4){0.f, 0.f, 0.f, 0.f};

  for (int k0 = 0; k0 < K; k0 += 32) {
    __syncthreads();
#pragma unroll
    for (int j = 0; j < 2; ++j) {
      int c = w * 64 + j * 256 + l;   // chunk id 0..511, 16B each
      int row = c >> 2, kb = c & 3;   // 4 chunks (32 bf16) per row
      gload16(A + (size_t)(m0 + row) * K + k0 + kb * 8, &As[(w * 64 + j * 256) * 8]);
      gload16(Bt + (size_t)(n0 + row) * K + k0 + kb * 8, &Bs[(w * 64 + j * 256) * 8]);
    }
    __syncthreads();
    bf16x8 af[4], bf[4];
#pragma unroll
    for (int m = 0; m < 4; ++m)
      af[m] = *(const bf16x8*)&As[(wr * 64 + m * 16 + lr) * 32 + lg * 8];
#pragma unroll
    for (int n = 0; n < 4; ++n)
      bf[n] = *(const bf16x8*)&Bs[(wc * 64 + n * 16 + lr) * 32 + lg * 8];
#pragma unroll
    for (int m = 0; m < 4; ++m)
#pragma unroll
      for (int n = 0; n < 4; ++n)
        acc[m][n] = __builtin_amdgcn_mfma_f32_16x16x32_bf16(af[m], bf[n], acc[m][n], 0, 0, 0);
  }
#pragma unroll
  for (int m = 0; m < 4; ++m)
#pragma unroll
    for (int n = 0; n < 4; ++n)
#pragma unroll
      for (int r = 0; r < 4; ++r) {
        int row = m0 + wr * 64 + m * 16 + lg * 4 + r;
        int col = n0 + wc * 64 + n * 16 + lr;
        float v = acc[m][n][r];
        if (OUTBF)
          ((u16*)Cout)[(size_t)row * N + col] = f2bf(v);
        else
          ((float*)Cout)[(size_t)row * N + col] = v;
      }
}

// ------------- RoPE: qkv [4096][3072] bf16 -> dst [B][nh][S][64] bf16 -------------
__global__ __launch_bounds__(256) void rope_kernel(const u16* __restrict__ qkv, const float* __restrict__ fcos,
                                                   const float* __restrict__ fsin, u16* __restrict__ dst,
                                                   int nhs /*log2 nheads*/, int col0) {
  int idx = blockIdx.x * 256 + threadIdx.x;
  int p = idx & 31;
  int h = (idx >> 5) & ((1 << nhs) - 1);
  int t = idx >> (5 + nhs);
  int s = t & 2047, b = t >> 11;
  unsigned v = *(const unsigned*)(qkv + (size_t)t * 3072 + col0 + h * 64 + 2 * p);
  float xr = bf2f((u16)(v & 0xffff)), xi = bf2f((u16)(v >> 16));
  float c = fcos[s * 32 + p], sn = fsin[s * 32 + p];
  float orr = xr * c - xi * sn;
  float oii = xr * sn + xi * c;
  unsigned o = (unsigned)f2bf(orr) | ((unsigned)f2bf(oii) << 16);
  *(unsigned*)(dst + (((size_t)((b << nhs) + h) * 2048 + s) * 64 + 2 * p)) = o;
}

// ------------- V transpose: qkv cols [2560..3072) -> vT [(b*8+kv)*64+d][S] -------------
__global__ __launch_bounds__(256) void vtrans(const u16* __restrict__ qkv, u16* __restrict__ vT) {
  __shared__ u16 tile[32][33];
  int c0 = blockIdx.x * 32, t0 = blockIdx.y * 32;
  int tx = threadIdx.x, ty = threadIdx.y;
#pragma unroll
  for (int i = 0; i < 4; ++i)
    tile[ty + i * 8][tx] = qkv[(size_t)(t0 + ty + i * 8) * 3072 + 2560 + c0 + tx];
  __syncthreads();
#pragma unroll
  for (int i = 0; i < 4; ++i) {
    int c = c0 + ty + i * 8;
    int tok = t0 + tx;
    vT[((size_t)((tok >> 11) * 8 + (c >> 6)) * 64 + (c & 63)) * 2048 + (tok & 2047)] = tile[tx][ty + i * 8];
  }
}

// ------------- Flash attention, swapped-QK 32x32 MFMA, in-register softmax -------------
// Q [B*H][S][64], K [B*KV][S][64], Vt [B*KV][64][S], mask [S][S] f32, Ao [B*S][2048] bf16
// 4 waves/block; each wave: 32 q rows. KV tile = 64 keys, double-buffered LDS, XOR-swizzled.
// P stays lane-resident (no cross-lane exchange): V fragments are assembled from two
// ds_read_b64 so that slot j holds key (j&3)+8*(j>>2)+4*hi, matching P's natural layout.
__global__ __launch_bounds__(256, 3) void attn(const u16* __restrict__ Q, const u16* __restrict__ Kb,
                                               const u16* __restrict__ Vt, const float* __restrict__ mask,
                                               u16* __restrict__ Ao) {
  __shared__ u16 Ks[2][4096];
  __shared__ u16 Vs[2][4096];
  __shared__ float cbuf[128];
  const int bid = blockIdx.x;
  const int qt = bid & 15, h = (bid >> 4) & 31, b = bid >> 9;
  const int kv = h >> 2;
  const int tid = threadIdx.x, w = tid >> 6, l = tid & 63;
  const int lq = l & 31, hi = l >> 5;

  const float SCL = 0.125f;
  const float L2E = 1.44269504088896f;

  // Q fragments (B-operand): lane lq = q col, d = t*16 + hi*8 + j
  const u16* Qb = Q + ((size_t)((b * 32 + h) * 2048 + qt * 128 + w * 32 + lq)) * 64;
  bf16x8 qf[4];
#pragma unroll
  for (int t = 0; t < 4; ++t)
    qf[t] = *(const bf16x8*)(Qb + t * 16 + hi * 8);

  const u16* Ksrc = Kb + (size_t)(b * 8 + kv) * 2048 * 64;
  const u16* Vsrc = Vt + (size_t)(b * 8 + kv) * 64 * 2048;
  const float* Mrow = mask + (size_t)(qt * 128 + w * 32 + lq) * 2048;

  f32x16 o0, o1;
#pragma unroll
  for (int i = 0; i < 16; ++i) { o0[i] = 0.f; o1[i] = 0.f; }
  float mrun = -3.0e38f, lrun = 0.f;

  // stage tile kt2 into buffer bu2 (K [64 keys][64 d], V^T [64 d][64 keys]; both XOR pre-swizzled)
  auto stage = [&](int kt2, int bu2) {
#pragma unroll
    for (int j = 0; j < 2; ++j) {
      int c = w * 64 + j * 256 + l;       // 16B chunk id 0..511
      int row = c >> 3, cc = c & 7;
      int sc_ = (cc ^ (row & 7)) * 8;     // pre-swizzled source chunk (elements)
      gload16(Ksrc + (size_t)(kt2 * 64 + row) * 64 + sc_, &Ks[bu2][(w * 64 + j * 256) * 8]);
      gload16(Vsrc + (size_t)row * 2048 + kt2 * 64 + sc_, &Vs[bu2][(w * 64 + j * 256) * 8]);
    }
  };

  stage(0, 0);
  __syncthreads();

  for (int kt = 0; kt < 32; ++kt) {
    const int bu = kt & 1;
    if (kt < 31) stage(kt + 1, bu ^ 1);
    const u16* KL = Ks[bu];
    const u16* VL = Vs[bu];

    // ---- QK^T swapped: S[k][q] = sum_d K[k][d] Q[q][d], per 32-k subtile ----
    f32x16 sS[2];
#pragma unroll
    for (int ks = 0; ks < 2; ++ks) {
      f32x16 a;
#pragma unroll
      for (int i = 0; i < 16; ++i) a[i] = 0.f;
      __builtin_amdgcn_s_setprio(1);
#pragma unroll
      for (int t = 0; t < 4; ++t) {
        bf16x8 kf = *(const bf16x8*)(KL + (size_t)(lq + 32 * ks) * 64 + ((((t << 1) + hi) ^ (lq & 7)) << 3));
        a = __builtin_amdgcn_mfma_f32_32x32x16_bf16(kf, qf[t], a, 0, 0, 0);
      }
      __builtin_amdgcn_s_setprio(0);
      // scale + mask: lane's 16 scores are S[k=(r&3)+8*(r>>2)+4*hi][q=lq] -> 4x float4 mask loads
#pragma unroll
      for (int g = 0; g < 4; ++g) {
        f32x4 mk = *(const f32x4*)(Mrow + kt * 64 + ks * 32 + g * 8 + hi * 4);
#pragma unroll
        for (int i = 0; i < 4; ++i) sS[ks][g * 4 + i] = a[g * 4 + i] * SCL + mk[i];
      }
    }

    // ---- row max (lane-local 31 fmax + half-exchange via shfl_xor 32) ----
    float tmax = sS[0][0];
#pragma unroll
    for (int i = 1; i < 16; ++i) tmax = fmaxf(tmax, sS[0][i]);
#pragma unroll
    for (int i = 0; i < 16; ++i) tmax = fmaxf(tmax, sS[1][i]);
    tmax = fmaxf(tmax, __shfl_xor(tmax, 32));

    // ---- defer-max rescale (T13, THR=8 nats) ----
    if (!__all(tmax - mrun <= 8.0f)) {
      float mnew = fmaxf(mrun, tmax);
      float corr = exp2f((mrun - mnew) * L2E);
      mrun = mnew;
      lrun *= corr;
      if (l < 32) cbuf[(w << 5) + l] = corr;
      asm volatile("s_waitcnt lgkmcnt(0)" ::: "memory");
#pragma unroll
      for (int r = 0; r < 16; ++r) {
        float c = cbuf[(w << 5) + ((r & 3) + 8 * (r >> 2) + 4 * hi)];
        o0[r] *= c; o1[r] *= c;
      }
    }

    // ---- exp + row sum ----
    float psum = 0.f;
#pragma unroll
    for (int ks = 0; ks < 2; ++ks)
#pragma unroll
      for (int i = 0; i < 16; ++i) {
        float p = exp2f((sS[ks][i] - mrun) * L2E);
        sS[ks][i] = p;
        psum += p;
      }
    psum += __shfl_xor(psum, 32);
    lrun += psum;

    // ---- P -> bf16 words (lane-resident; slot j holds key (j&3)+8*(j>>2)+4hi), then PV ----
#pragma unroll
    for (int ks = 0; ks < 2; ++ks) {
      unsigned uu0 = cvtpk(sS[ks][0], sS[ks][1]);
      unsigned uu1 = cvtpk(sS[ks][2], sS[ks][3]);
      unsigned uu2 = cvtpk(sS[ks][4], sS[ks][5]);
      unsigned uu3 = cvtpk(sS[ks][6], sS[ks][7]);
      unsigned uu4 = cvtpk(sS[ks][8], sS[ks][9]);
      unsigned uu5 = cvtpk(sS[ks][10], sS[ks][11]);
      unsigned uu6 = cvtpk(sS[ks][12], sS[ks][13]);
      unsigned uu7 = cvtpk(sS[ks][14], sS[ks][15]);
      __builtin_amdgcn_s_setprio(1);
#pragma unroll
      for (int t = 0; t < 2; ++t) {
        u32x4 wv_;
        if (t == 0) wv_ = (u32x4){uu0, uu1, uu2, uu3};
        else        wv_ = (u32x4){uu4, uu5, uu6, uu7};
        bf16x8 pa = __builtin_bit_cast(bf16x8, wv_);
#pragma unroll
        for (int dblk = 0; dblk < 2; ++dblk) {
          int vrow = lq + 32 * dblk;
          // V fragment: slots 0..3 = keys ks*32+t*16+4hi+{0..3}, slots 4..7 = +8
          const char* Vrow = (const char*)VL + (size_t)vrow * 128 + (hi << 3);
          int c1 = ((ks << 2) + (t << 1)) ^ (lq & 7);
          int c2 = ((ks << 2) + (t << 1) + 1) ^ (lq & 7);
          u32x2 va = *(const u32x2*)(Vrow + (c1 << 4));
          u32x2 vb2 = *(const u32x2*)(Vrow + (c2 << 4));
          u32x4 vv = {va[0], va[1], vb2[0], vb2[1]};
          bf16x8 vfrag = __builtin_bit_cast(bf16x8, vv);
          if (dblk == 0) o0 = __builtin_amdgcn_mfma_f32_32x32x16_bf16(pa, vfrag, o0, 0, 0, 0);
          else           o1 = __builtin_amdgcn_mfma_f32_32x32x16_bf16(pa, vfrag, o1, 0, 0, 0);
        }
      }
      __builtin_amdgcn_s_setprio(0);
    }

    __syncthreads();
  }

  // ---- epilogue: broadcast 1/lrun via LDS, normalize, store ----
  if (l < 32) cbuf[(w << 5) + l] = 1.0f / lrun;
  asm volatile("s_waitcnt lgkmcnt(0)" ::: "memory");
#pragma unroll
  for (int r = 0; r < 16; ++r) {
    int oq = (r & 3) + 8 * (r >> 2) + 4 * hi;
    float inv = cbuf[(w << 5) + oq];
    int srow = qt * 128 + w * 32 + oq;
    size_t tok = (size_t)(b * 2048 + srow);
    Ao[tok * 2048 + h * 64 + lq]      = f2bf(o0[r] * inv);
    Ao[tok * 2048 + h * 64 + 32 + lq] = f2bf(o1[r] * inv);
  }
}

extern "C" void kernel_launch(void* const* d_in, const int* in_sizes, int n_in,
                              void* d_out, int out_size, void* d_ws, size_t ws_size,
                              hipStream_t stream) {
  const float* x    = (const float*)d_in[0];
  const float* fcos = (const float*)d_in[1];
  const float* fsin = (const float*)d_in[2];
  const float* mask = (const float*)d_in[3];
  const float* wq   = (const float*)d_in[4];
  const float* wk   = (const float*)d_in[5];
  const float* wv   = (const float*)d_in[6];
  const float* wo   = (const float*)d_in[7];
  float* out = (float*)d_out;

  // workspace layout (u16 elements), total ~79.7 MB
  u16* ws  = (u16*)d_ws;
  u16* xb  = ws;                       // 8,388,608   x bf16; later reused as attn_out
  u16* wT  = ws + 8388608;             // 6,291,456   wqkvT [3072][2048]; later woT [2048][2048]
  u16* qkv = ws + 14680064;            // 12,582,912  qkv [4096][3072]
  u16* qb  = ws + 27262976;            // 8,388,608   Q [B][32][S][64]
  u16* kb  = ws + 35651584;            // 2,097,152   K [B][8][S][64]
  u16* vT  = ws + 37748736;            // 2,097,152   V^T [B*8][64][S]

  cvt_x<<<8192, 256, 0, stream>>>(x, xb);
  transpose_cvt<<<dim3(64, 64), dim3(32, 8), 0, stream>>>(wq, wT, 2048, 2048);
  transpose_cvt<<<dim3(16, 64), dim3(32, 8), 0, stream>>>(wk, wT + (size_t)2048 * 2048, 2048, 512);
  transpose_cvt<<<dim3(16, 64), dim3(32, 8), 0, stream>>>(wv, wT + (size_t)2560 * 2048, 2048, 512);
  gemm_bt<1><<<dim3(24, 32), 256, 0, stream>>>(xb, wT, qkv, 4096, 3072, 2048);
  transpose_cvt<<<dim3(64, 64), dim3(32, 8), 0, stream>>>(wo, wT, 2048, 2048);  // after gemm1 (wT reuse)
  rope_kernel<<<16384, 256, 0, stream>>>(qkv, fcos, fsin, qb, 5, 0);
  rope_kernel<<<4096, 256, 0, stream>>>(qkv, fcos, fsin, kb, 3, 2048);
  vtrans<<<dim3(16, 128), dim3(32, 8), 0, stream>>>(qkv, vT);
  attn<<<1024, 256, 0, stream>>>(qb, kb, vT, mask, xb);
  gemm_bt<0><<<dim3(16, 32), 256, 0, stream>>>(xb, wT, out, 4096, 2048, 2048);
}

// Round 4
// 310.920 us; speedup vs baseline: 1.3530x; 1.2307x over previous
//
#include <hip/hip_runtime.h>

typedef unsigned short u16;
typedef __bf16 bf16x8 __attribute__((ext_vector_type(8)));
typedef float f32x4 __attribute__((ext_vector_type(4)));
typedef float f32x16 __attribute__((ext_vector_type(16)));
typedef unsigned short u16x4 __attribute__((ext_vector_type(4)));
typedef unsigned int u32x2 __attribute__((ext_vector_type(2)));
typedef unsigned int u32x4 __attribute__((ext_vector_type(4)));

typedef __attribute__((address_space(1))) const unsigned int* gas_t;
typedef __attribute__((address_space(3))) unsigned int* las_t;

__device__ __forceinline__ void gload16(const void* gsrc, void* ldst) {
  __builtin_amdgcn_global_load_lds((gas_t)gsrc, (las_t)ldst, 16, 0, 0);
}

__device__ __forceinline__ u16 f2bf(float f) {
  unsigned u = __builtin_bit_cast(unsigned, f);
  unsigned r = u + 0x7fffu + ((u >> 16) & 1u);
  return (u16)(r >> 16);
}
__device__ __forceinline__ float bf2f(u16 h) {
  unsigned u = ((unsigned)h) << 16;
  return __builtin_bit_cast(float, u);
}
__device__ __forceinline__ unsigned cvtpk(float lo, float hi) {
  unsigned r;
  asm("v_cvt_pk_bf16_f32 %0, %1, %2" : "=v"(r) : "v"(lo), "v"(hi));
  return r;
}

// ---------------- x -> bf16 ----------------
__global__ __launch_bounds__(256) void cvt_x(const float* __restrict__ x, u16* __restrict__ xb) {
  int i = blockIdx.x * 256 + threadIdx.x;
  f32x4 v = ((const f32x4*)x)[i];
  u16x4 o = { f2bf(v[0]), f2bf(v[1]), f2bf(v[2]), f2bf(v[3]) };
  ((u16x4*)xb)[i] = o;
}

// ------------- transpose + convert weights: in [K][N] f32 -> out [N][K] bf16 -------------
__global__ __launch_bounds__(256) void transpose_cvt(const float* __restrict__ in, u16* __restrict__ out,
                                                     int K, int N) {
  __shared__ float tile[32][33];
  int n0 = blockIdx.x * 32, k0 = blockIdx.y * 32;
  int tx = threadIdx.x, ty = threadIdx.y; // 32 x 8
#pragma unroll
  for (int i = 0; i < 4; ++i)
    tile[ty + i * 8][tx] = in[(size_t)(k0 + ty + i * 8) * N + n0 + tx];
  __syncthreads();
#pragma unroll
  for (int i = 0; i < 4; ++i)
    out[(size_t)(n0 + ty + i * 8) * K + k0 + tx] = f2bf(tile[tx][ty + i * 8]);
}

// ------------- GEMM: A [M][K] bf16, Bt [N][K] bf16 -> C [M][N] (bf16 or f32) -------------
template <int OUTBF>
__global__ __launch_bounds__(256) void gemm_bt(const u16* __restrict__ A, const u16* __restrict__ Bt,
                                               void* __restrict__ Cout, int M, int N, int K) {
  __shared__ u16 As[128 * 32];
  __shared__ u16 Bs[128 * 32];
  const int tid = threadIdx.x;
  const int w = tid >> 6, l = tid & 63, lg = l >> 4, lr = l & 15;
  const int m0 = blockIdx.y * 128, n0 = blockIdx.x * 128;
  const int wr = w >> 1, wc = w & 1;
  f32x4 acc[4][4];
#pragma unroll
  for (int m = 0; m < 4; ++m)
#pragma unroll
    for (int n = 0; n < 4; ++n) acc[m][n] = (f32x4){0.f, 0.f, 0.f, 0.f};

  for (int k0 = 0; k0 < K; k0 += 32) {
    __syncthreads();
#pragma unroll
    for (int j = 0; j < 2; ++j) {
      int c = w * 64 + j * 256 + l;   // chunk id 0..511, 16B each
      int row = c >> 2, kb = c & 3;   // 4 chunks (32 bf16) per row
      gload16(A + (size_t)(m0 + row) * K + k0 + kb * 8, &As[(w * 64 + j * 256) * 8]);
      gload16(Bt + (size_t)(n0 + row) * K + k0 + kb * 8, &Bs[(w * 64 + j * 256) * 8]);
    }
    __syncthreads();
    bf16x8 af[4], bf[4];
#pragma unroll
    for (int m = 0; m < 4; ++m)
      af[m] = *(const bf16x8*)&As[(wr * 64 + m * 16 + lr) * 32 + lg * 8];
#pragma unroll
    for (int n = 0; n < 4; ++n)
      bf[n] = *(const bf16x8*)&Bs[(wc * 64 + n * 16 + lr) * 32 + lg * 8];
#pragma unroll
    for (int m = 0; m < 4; ++m)
#pragma unroll
      for (int n = 0; n < 4; ++n)
        acc[m][n] = __builtin_amdgcn_mfma_f32_16x16x32_bf16(af[m], bf[n], acc[m][n], 0, 0, 0);
  }
#pragma unroll
  for (int m = 0; m < 4; ++m)
#pragma unroll
    for (int n = 0; n < 4; ++n)
#pragma unroll
      for (int r = 0; r < 4; ++r) {
        int row = m0 + wr * 64 + m * 16 + lg * 4 + r;
        int col = n0 + wc * 64 + n * 16 + lr;
        float v = acc[m][n][r];
        if (OUTBF)
          ((u16*)Cout)[(size_t)row * N + col] = f2bf(v);
        else
          ((float*)Cout)[(size_t)row * N + col] = v;
      }
}

// ------------- RoPE: qkv [4096][3072] bf16 -> dst [B][nh][S][64] bf16 -------------
__global__ __launch_bounds__(256) void rope_kernel(const u16* __restrict__ qkv, const float* __restrict__ fcos,
                                                   const float* __restrict__ fsin, u16* __restrict__ dst,
                                                   int nhs /*log2 nheads*/, int col0) {
  int idx = blockIdx.x * 256 + threadIdx.x;
  int p = idx & 31;
  int h = (idx >> 5) & ((1 << nhs) - 1);
  int t = idx >> (5 + nhs);
  int s = t & 2047, b = t >> 11;
  unsigned v = *(const unsigned*)(qkv + (size_t)t * 3072 + col0 + h * 64 + 2 * p);
  float xr = bf2f((u16)(v & 0xffff)), xi = bf2f((u16)(v >> 16));
  float c = fcos[s * 32 + p], sn = fsin[s * 32 + p];
  float orr = xr * c - xi * sn;
  float oii = xr * sn + xi * c;
  unsigned o = (unsigned)f2bf(orr) | ((unsigned)f2bf(oii) << 16);
  *(unsigned*)(dst + (((size_t)((b << nhs) + h) * 2048 + s) * 64 + 2 * p)) = o;
}

// ------------- V transpose: qkv cols [2560..3072) -> vT [(b*8+kv)*64+d][S] -------------
__global__ __launch_bounds__(256) void vtrans(const u16* __restrict__ qkv, u16* __restrict__ vT) {
  __shared__ u16 tile[32][33];
  int c0 = blockIdx.x * 32, t0 = blockIdx.y * 32;
  int tx = threadIdx.x, ty = threadIdx.y;
#pragma unroll
  for (int i = 0; i < 4; ++i)
    tile[ty + i * 8][tx] = qkv[(size_t)(t0 + ty + i * 8) * 3072 + 2560 + c0 + tx];
  __syncthreads();
#pragma unroll
  for (int i = 0; i < 4; ++i) {
    int c = c0 + ty + i * 8;
    int tok = t0 + tx;
    vT[((size_t)((tok >> 11) * 8 + (c >> 6)) * 64 + (c & 63)) * 2048 + (tok & 2047)] = tile[tx][ty + i * 8];
  }
}

// ------------- mask tile flags: Fl[qt] bit kt = (128q x 64k tile has any nonzero) -------------
__global__ __launch_bounds__(256) void mask_flags(const float* __restrict__ mask, unsigned* __restrict__ Fl) {
  int qt = blockIdx.x, kt = blockIdx.y;
  int t = threadIdx.x;
  int row = qt * 128 + (t >> 1);
  const f32x4* p = (const f32x4*)(mask + (size_t)row * 2048 + kt * 64 + (t & 1) * 32);
  bool any = false;
#pragma unroll
  for (int j = 0; j < 8; ++j) {
    f32x4 v = p[j];
    any |= (v[0] != 0.f) | (v[1] != 0.f) | (v[2] != 0.f) | (v[3] != 0.f);
  }
  if (__any(any) && (t & 63) == 0) atomicOr(&Fl[qt], 1u << kt);
}

// ------------- Flash attention, swapped-QK 32x32 MFMA, in-register softmax -------------
// Q [B*H][S][64], K [B*KV][S][64], Vt [B*KV][64][S], Fl mask-tile flags, Ao [B*S][2048] bf16
// 4 waves/block; each wave: 32 q rows. KV tile = 64 keys, double-buffered LDS, XOR-swizzled.
// Scores stay RAW (folding: p = exp2(a*C - mrun2), C = SCL*log2(e)); mask folds as a += mk*8.
__global__ __launch_bounds__(256, 4) void attn(const u16* __restrict__ Q, const u16* __restrict__ Kb,
                                               const u16* __restrict__ Vt, const float* __restrict__ mask,
                                               const unsigned* __restrict__ Fl, u16* __restrict__ Ao) {
  __shared__ u16 Ks[2][4096];
  __shared__ u16 Vs[2][4096];
  __shared__ float cbuf[128];
  const int bid = blockIdx.x;
  const int qt = bid & 15, h = (bid >> 4) & 31, b = bid >> 9;
  const int kv = h >> 2;
  const int tid = threadIdx.x, w = tid >> 6, l = tid & 63;
  const int lq = l & 31, hi = l >> 5;

  const float C = 0.125f * 1.44269504088896f;  // SCL * log2(e)
  const float THR = 11.5416f;                  // 8 nats in log2 units

  // Q fragments (B-operand): lane lq = q col, d = t*16 + hi*8 + j
  const u16* Qb = Q + ((size_t)((b * 32 + h) * 2048 + qt * 128 + w * 32 + lq)) * 64;
  bf16x8 qf[4];
#pragma unroll
  for (int t = 0; t < 4; ++t)
    qf[t] = *(const bf16x8*)(Qb + t * 16 + hi * 8);

  const u16* Ksrc = Kb + (size_t)(b * 8 + kv) * 2048 * 64;
  const u16* Vsrc = Vt + (size_t)(b * 8 + kv) * 64 * 2048;
  const float* Mrow = mask + (size_t)(qt * 128 + w * 32 + lq) * 2048;
  const unsigned flagbits = Fl[qt];

  f32x16 o0, o1;
#pragma unroll
  for (int i = 0; i < 16; ++i) { o0[i] = 0.f; o1[i] = 0.f; }
  float mrun2 = -3.0e38f, lrun = 0.f;

  // stage tile kt2 into buffer bu2 (K [64 keys][64 d], V^T [64 d][64 keys]; both XOR pre-swizzled)
  auto stage = [&](int kt2, int bu2) {
#pragma unroll
    for (int j = 0; j < 2; ++j) {
      int c = w * 64 + j * 256 + l;       // 16B chunk id 0..511
      int row = c >> 3, cc = c & 7;
      int sc_ = (cc ^ (row & 7)) * 8;     // pre-swizzled source chunk (elements)
      gload16(Ksrc + (size_t)(kt2 * 64 + row) * 64 + sc_, &Ks[bu2][(w * 64 + j * 256) * 8]);
      gload16(Vsrc + (size_t)row * 2048 + kt2 * 64 + sc_, &Vs[bu2][(w * 64 + j * 256) * 8]);
    }
  };

  stage(0, 0);
  __syncthreads();

  for (int kt = 0; kt < 32; ++kt) {
    const int bu = kt & 1;
    if (kt < 31) stage(kt + 1, bu ^ 1);
    const u16* KL = Ks[bu];
    const u16* VL = Vs[bu];

    // ---- QK^T swapped: raw scores a[k][q] = sum_d K[k][d] Q[q][d] ----
    f32x16 sS[2];
#pragma unroll
    for (int ks = 0; ks < 2; ++ks) {
      f32x16 a;
#pragma unroll
      for (int i = 0; i < 16; ++i) a[i] = 0.f;
      __builtin_amdgcn_s_setprio(1);
#pragma unroll
      for (int t = 0; t < 4; ++t) {
        bf16x8 kf = *(const bf16x8*)(KL + (size_t)(lq + 32 * ks) * 64 + ((((t << 1) + hi) ^ (lq & 7)) << 3));
        a = __builtin_amdgcn_mfma_f32_32x32x16_bf16(kf, qf[t], a, 0, 0, 0);
      }
      __builtin_amdgcn_s_setprio(0);
      sS[ks] = a;
    }

    // ---- rare path: fold mask into raw scores (a += mk * 8, since raw*SCL = real) ----
    if (flagbits & (1u << kt)) {
#pragma unroll
      for (int ks = 0; ks < 2; ++ks)
#pragma unroll
        for (int g = 0; g < 4; ++g) {
          f32x4 mk = *(const f32x4*)(Mrow + kt * 64 + ks * 32 + g * 8 + hi * 4);
#pragma unroll
          for (int i = 0; i < 4; ++i) sS[ks][g * 4 + i] = fmaf(mk[i], 8.0f, sS[ks][g * 4 + i]);
        }
    }

    // ---- row max on raw scores (tree), then to log2 units ----
    float ta = fmaxf(sS[0][0], sS[0][1]), tb = fmaxf(sS[0][2], sS[0][3]);
#pragma unroll
    for (int i = 4; i < 16; i += 4) {
      ta = fmaxf(ta, fmaxf(sS[0][i], sS[0][i + 1]));
      tb = fmaxf(tb, fmaxf(sS[0][i + 2], sS[0][i + 3]));
    }
#pragma unroll
    for (int i = 0; i < 16; i += 4) {
      ta = fmaxf(ta, fmaxf(sS[1][i], sS[1][i + 1]));
      tb = fmaxf(tb, fmaxf(sS[1][i + 2], sS[1][i + 3]));
    }
    float tmax = fmaxf(ta, tb);
    tmax = fmaxf(tmax, __shfl_xor(tmax, 32));
    float t2 = tmax * C;

    // ---- defer-max rescale (T13) ----
    if (!__all(t2 - mrun2 <= THR)) {
      float mnew = fmaxf(mrun2, t2);
      float corr = exp2f(mrun2 - mnew);
      mrun2 = mnew;
      lrun *= corr;
      if (l < 32) cbuf[(w << 5) + l] = corr;
      asm volatile("s_waitcnt lgkmcnt(0)" ::: "memory");
#pragma unroll
      for (int r = 0; r < 16; ++r) {
        float c = cbuf[(w << 5) + ((r & 3) + 8 * (r >> 2) + 4 * hi)];
        o0[r] *= c; o1[r] *= c;
      }
    }

    // ---- p = exp2(a*C - mrun2)  (single fma + exp per score), tree sum ----
    float ps0 = 0.f, ps1 = 0.f, ps2 = 0.f, ps3 = 0.f;
#pragma unroll
    for (int ks = 0; ks < 2; ++ks)
#pragma unroll
      for (int i = 0; i < 16; i += 4) {
        float p0 = exp2f(sS[ks][i] * C - mrun2);
        float p1 = exp2f(sS[ks][i + 1] * C - mrun2);
        float p2 = exp2f(sS[ks][i + 2] * C - mrun2);
        float p3 = exp2f(sS[ks][i + 3] * C - mrun2);
        sS[ks][i] = p0; sS[ks][i + 1] = p1; sS[ks][i + 2] = p2; sS[ks][i + 3] = p3;
        ps0 += p0; ps1 += p1; ps2 += p2; ps3 += p3;
      }
    float psum = (ps0 + ps1) + (ps2 + ps3);
    psum += __shfl_xor(psum, 32);
    lrun += psum;

    // ---- P -> bf16 words (lane-resident; slot j holds key (j&3)+8*(j>>2)+4hi), then PV ----
#pragma unroll
    for (int ks = 0; ks < 2; ++ks) {
      unsigned uu0 = cvtpk(sS[ks][0], sS[ks][1]);
      unsigned uu1 = cvtpk(sS[ks][2], sS[ks][3]);
      unsigned uu2 = cvtpk(sS[ks][4], sS[ks][5]);
      unsigned uu3 = cvtpk(sS[ks][6], sS[ks][7]);
      unsigned uu4 = cvtpk(sS[ks][8], sS[ks][9]);
      unsigned uu5 = cvtpk(sS[ks][10], sS[ks][11]);
      unsigned uu6 = cvtpk(sS[ks][12], sS[ks][13]);
      unsigned uu7 = cvtpk(sS[ks][14], sS[ks][15]);
      __builtin_amdgcn_s_setprio(1);
#pragma unroll
      for (int t = 0; t < 2; ++t) {
        u32x4 wv_;
        if (t == 0) wv_ = (u32x4){uu0, uu1, uu2, uu3};
        else        wv_ = (u32x4){uu4, uu5, uu6, uu7};
        bf16x8 pa = __builtin_bit_cast(bf16x8, wv_);
#pragma unroll
        for (int dblk = 0; dblk < 2; ++dblk) {
          int vrow = lq + 32 * dblk;
          // V fragment: slots 0..3 = keys ks*32+t*16+4hi+{0..3}, slots 4..7 = +8
          const char* Vrow = (const char*)VL + (size_t)vrow * 128 + (hi << 3);
          int c1 = ((ks << 2) + (t << 1)) ^ (lq & 7);
          int c2 = ((ks << 2) + (t << 1) + 1) ^ (lq & 7);
          u32x2 va = *(const u32x2*)(Vrow + (c1 << 4));
          u32x2 vb2 = *(const u32x2*)(Vrow + (c2 << 4));
          u32x4 vv = {va[0], va[1], vb2[0], vb2[1]};
          bf16x8 vfrag = __builtin_bit_cast(bf16x8, vv);
          if (dblk == 0) o0 = __builtin_amdgcn_mfma_f32_32x32x16_bf16(pa, vfrag, o0, 0, 0, 0);
          else           o1 = __builtin_amdgcn_mfma_f32_32x32x16_bf16(pa, vfrag, o1, 0, 0, 0);
        }
      }
      __builtin_amdgcn_s_setprio(0);
    }

    __syncthreads();
  }

  // ---- epilogue: broadcast 1/lrun via LDS, normalize, store ----
  if (l < 32) cbuf[(w << 5) + l] = 1.0f / lrun;
  asm volatile("s_waitcnt lgkmcnt(0)" ::: "memory");
#pragma unroll
  for (int r = 0; r < 16; ++r) {
    int oq = (r & 3) + 8 * (r >> 2) + 4 * hi;
    float inv = cbuf[(w << 5) + oq];
    int srow = qt * 128 + w * 32 + oq;
    size_t tok = (size_t)(b * 2048 + srow);
    Ao[tok * 2048 + h * 64 + lq]      = f2bf(o0[r] * inv);
    Ao[tok * 2048 + h * 64 + 32 + lq] = f2bf(o1[r] * inv);
  }
}

extern "C" void kernel_launch(void* const* d_in, const int* in_sizes, int n_in,
                              void* d_out, int out_size, void* d_ws, size_t ws_size,
                              hipStream_t stream) {
  const float* x    = (const float*)d_in[0];
  const float* fcos = (const float*)d_in[1];
  const float* fsin = (const float*)d_in[2];
  const float* mask = (const float*)d_in[3];
  const float* wq   = (const float*)d_in[4];
  const float* wk   = (const float*)d_in[5];
  const float* wv   = (const float*)d_in[6];
  const float* wo   = (const float*)d_in[7];
  float* out = (float*)d_out;

  // workspace layout (u16 elements), total ~79.7 MB
  u16* ws  = (u16*)d_ws;
  u16* xb  = ws;                       // 8,388,608   x bf16; later reused as attn_out
  u16* wT  = ws + 8388608;             // 6,291,456   wqkvT [3072][2048]; later woT [2048][2048]
  u16* qkv = ws + 14680064;            // 12,582,912  qkv [4096][3072]; first 64B reused as mask flags
  u16* qb  = ws + 27262976;            // 8,388,608   Q [B][32][S][64]
  u16* kb  = ws + 35651584;            // 2,097,152   K [B][8][S][64]
  u16* vT  = ws + 37748736;            // 2,097,152   V^T [B*8][64][S]
  unsigned* Fl = (unsigned*)qkv;       // 16 u32 (qkv is dead by the time flags are written)

  cvt_x<<<8192, 256, 0, stream>>>(x, xb);
  transpose_cvt<<<dim3(64, 64), dim3(32, 8), 0, stream>>>(wq, wT, 2048, 2048);
  transpose_cvt<<<dim3(16, 64), dim3(32, 8), 0, stream>>>(wk, wT + (size_t)2048 * 2048, 2048, 512);
  transpose_cvt<<<dim3(16, 64), dim3(32, 8), 0, stream>>>(wv, wT + (size_t)2560 * 2048, 2048, 512);
  gemm_bt<1><<<dim3(24, 32), 256, 0, stream>>>(xb, wT, qkv, 4096, 3072, 2048);
  transpose_cvt<<<dim3(64, 64), dim3(32, 8), 0, stream>>>(wo, wT, 2048, 2048);  // after gemm1 (wT reuse)
  rope_kernel<<<16384, 256, 0, stream>>>(qkv, fcos, fsin, qb, 5, 0);
  rope_kernel<<<4096, 256, 0, stream>>>(qkv, fcos, fsin, kb, 3, 2048);
  vtrans<<<dim3(16, 128), dim3(32, 8), 0, stream>>>(qkv, vT);
  hipMemsetAsync(Fl, 0, 16 * sizeof(unsigned), stream);   // qkv fully consumed above
  mask_flags<<<dim3(16, 32), 256, 0, stream>>>(mask, Fl);
  attn<<<1024, 256, 0, stream>>>(qb, kb, vT, mask, Fl, xb);
  gemm_bt<0><<<dim3(16, 32), 256, 0, stream>>>(xb, wT, out, 4096, 2048, 2048);
}

// Round 5
// 293.857 us; speedup vs baseline: 1.4316x; 1.0581x over previous
//
#include <hip/hip_runtime.h>

typedef unsigned short u16;
typedef __bf16 bf16x8 __attribute__((ext_vector_type(8)));
typedef float f32x4 __attribute__((ext_vector_type(4)));
typedef float f32x16 __attribute__((ext_vector_type(16)));
typedef unsigned short u16x4 __attribute__((ext_vector_type(4)));
typedef unsigned int u32x2 __attribute__((ext_vector_type(2)));
typedef unsigned int u32x4 __attribute__((ext_vector_type(4)));

typedef __attribute__((address_space(1))) const unsigned int* gas_t;
typedef __attribute__((address_space(3))) unsigned int* las_t;

__device__ __forceinline__ void gload16(const void* gsrc, void* ldst) {
  __builtin_amdgcn_global_load_lds((gas_t)gsrc, (las_t)ldst, 16, 0, 0);
}

__device__ __forceinline__ u16 f2bf(float f) {
  unsigned u = __builtin_bit_cast(unsigned, f);
  unsigned r = u + 0x7fffu + ((u >> 16) & 1u);
  return (u16)(r >> 16);
}
__device__ __forceinline__ float bf2f(u16 h) {
  unsigned u = ((unsigned)h) << 16;
  return __builtin_bit_cast(float, u);
}
__device__ __forceinline__ unsigned cvtpk(float lo, float hi) {
  unsigned r;
  asm("v_cvt_pk_bf16_f32 %0, %1, %2" : "=v"(r) : "v"(lo), "v"(hi));
  return r;
}
__device__ __forceinline__ float max3f(float a, float b, float c) {
  return fmaxf(fmaxf(a, b), c);
}

// ---------------- x -> bf16 ----------------
__global__ __launch_bounds__(256) void cvt_x(const float* __restrict__ x, u16* __restrict__ xb) {
  int i = blockIdx.x * 256 + threadIdx.x;
  f32x4 v = ((const f32x4*)x)[i];
  u16x4 o = { f2bf(v[0]), f2bf(v[1]), f2bf(v[2]), f2bf(v[3]) };
  ((u16x4*)xb)[i] = o;
}

// ------------- transpose + convert weights: in [K][N] f32 -> out [N][K] bf16 -------------
__global__ __launch_bounds__(256) void transpose_cvt(const float* __restrict__ in, u16* __restrict__ out,
                                                     int K, int N) {
  __shared__ float tile[32][33];
  int n0 = blockIdx.x * 32, k0 = blockIdx.y * 32;
  int tx = threadIdx.x, ty = threadIdx.y; // 32 x 8
#pragma unroll
  for (int i = 0; i < 4; ++i)
    tile[ty + i * 8][tx] = in[(size_t)(k0 + ty + i * 8) * N + n0 + tx];
  __syncthreads();
#pragma unroll
  for (int i = 0; i < 4; ++i)
    out[(size_t)(n0 + ty + i * 8) * K + k0 + tx] = f2bf(tile[tx][ty + i * 8]);
}

// ------------- GEMM: A [M][K] bf16, Bt [N][K] bf16 -> C [M][N] (bf16 or f32) -------------
template <int OUTBF>
__global__ __launch_bounds__(256) void gemm_bt(const u16* __restrict__ A, const u16* __restrict__ Bt,
                                               void* __restrict__ Cout, int M, int N, int K) {
  __shared__ u16 As[128 * 32];
  __shared__ u16 Bs[128 * 32];
  const int tid = threadIdx.x;
  const int w = tid >> 6, l = tid & 63, lg = l >> 4, lr = l & 15;
  const int m0 = blockIdx.y * 128, n0 = blockIdx.x * 128;
  const int wr = w >> 1, wc = w & 1;
  f32x4 acc[4][4];
#pragma unroll
  for (int m = 0; m < 4; ++m)
#pragma unroll
    for (int n = 0; n < 4; ++n) acc[m][n] = (f32x4){0.f, 0.f, 0.f, 0.f};

  for (int k0 = 0; k0 < K; k0 += 32) {
    __syncthreads();
#pragma unroll
    for (int j = 0; j < 2; ++j) {
      int c = w * 64 + j * 256 + l;   // chunk id 0..511, 16B each
      int row = c >> 2, kb = c & 3;   // 4 chunks (32 bf16) per row
      gload16(A + (size_t)(m0 + row) * K + k0 + kb * 8, &As[(w * 64 + j * 256) * 8]);
      gload16(Bt + (size_t)(n0 + row) * K + k0 + kb * 8, &Bs[(w * 64 + j * 256) * 8]);
    }
    __syncthreads();
    bf16x8 af[4], bf[4];
#pragma unroll
    for (int m = 0; m < 4; ++m)
      af[m] = *(const bf16x8*)&As[(wr * 64 + m * 16 + lr) * 32 + lg * 8];
#pragma unroll
    for (int n = 0; n < 4; ++n)
      bf[n] = *(const bf16x8*)&Bs[(wc * 64 + n * 16 + lr) * 32 + lg * 8];
#pragma unroll
    for (int m = 0; m < 4; ++m)
#pragma unroll
      for (int n = 0; n < 4; ++n)
        acc[m][n] = __builtin_amdgcn_mfma_f32_16x16x32_bf16(af[m], bf[n], acc[m][n], 0, 0, 0);
  }
#pragma unroll
  for (int m = 0; m < 4; ++m)
#pragma unroll
    for (int n = 0; n < 4; ++n)
#pragma unroll
      for (int r = 0; r < 4; ++r) {
        int row = m0 + wr * 64 + m * 16 + lg * 4 + r;
        int col = n0 + wc * 64 + n * 16 + lr;
        float v = acc[m][n][r];
        if (OUTBF)
          ((u16*)Cout)[(size_t)row * N + col] = f2bf(v);
        else
          ((float*)Cout)[(size_t)row * N + col] = v;
      }
}

// ------------- RoPE: qkv [4096][3072] bf16 -> dst [B][nh][S][64] bf16 -------------
__global__ __launch_bounds__(256) void rope_kernel(const u16* __restrict__ qkv, const float* __restrict__ fcos,
                                                   const float* __restrict__ fsin, u16* __restrict__ dst,
                                                   int nhs /*log2 nheads*/, int col0) {
  int idx = blockIdx.x * 256 + threadIdx.x;
  int p = idx & 31;
  int h = (idx >> 5) & ((1 << nhs) - 1);
  int t = idx >> (5 + nhs);
  int s = t & 2047, b = t >> 11;
  unsigned v = *(const unsigned*)(qkv + (size_t)t * 3072 + col0 + h * 64 + 2 * p);
  float xr = bf2f((u16)(v & 0xffff)), xi = bf2f((u16)(v >> 16));
  float c = fcos[s * 32 + p], sn = fsin[s * 32 + p];
  float orr = xr * c - xi * sn;
  float oii = xr * sn + xi * c;
  unsigned o = (unsigned)f2bf(orr) | ((unsigned)f2bf(oii) << 16);
  *(unsigned*)(dst + (((size_t)((b << nhs) + h) * 2048 + s) * 64 + 2 * p)) = o;
}

// ------------- V transpose: qkv cols [2560..3072) -> vT [(b*8+kv)*64+d][S] -------------
// Token (key) columns are PERMUTED within each 16-group (swap bits 2<->3) so that a
// contiguous 16B chunk holds keys in MFMA B-operand slot order (j&3)+8*(j>>2)+4*hi.
__global__ __launch_bounds__(256) void vtrans(const u16* __restrict__ qkv, u16* __restrict__ vT) {
  __shared__ u16 tile[32][33];
  int c0 = blockIdx.x * 32, t0 = blockIdx.y * 32;
  int tx = threadIdx.x, ty = threadIdx.y;
#pragma unroll
  for (int i = 0; i < 4; ++i)
    tile[ty + i * 8][tx] = qkv[(size_t)(t0 + ty + i * 8) * 3072 + 2560 + c0 + tx];
  __syncthreads();
#pragma unroll
  for (int i = 0; i < 4; ++i) {
    int c = c0 + ty + i * 8;
    int tok = t0 + tx;
    int ts = (tok & ~15) | (tok & 3) | ((tok & 4) << 1) | ((tok & 8) >> 1); // swap bits 2,3
    vT[((size_t)((tok >> 11) * 8 + (c >> 6)) * 64 + (c & 63)) * 2048 + (ts & 2047)] = tile[tx][ty + i * 8];
  }
}

// ------------- mask tile flags: Fl[qt] bit kt = (128q x 64k tile has any nonzero) -------------
__global__ __launch_bounds__(256) void mask_flags(const float* __restrict__ mask, unsigned* __restrict__ Fl) {
  int qt = blockIdx.x, kt = blockIdx.y;
  int t = threadIdx.x;
  int row = qt * 128 + (t >> 1);
  const f32x4* p = (const f32x4*)(mask + (size_t)row * 2048 + kt * 64 + (t & 1) * 32);
  bool any = false;
#pragma unroll
  for (int j = 0; j < 8; ++j) {
    f32x4 v = p[j];
    any |= (v[0] != 0.f) | (v[1] != 0.f) | (v[2] != 0.f) | (v[3] != 0.f);
  }
  if (__any(any) && (t & 63) == 0) atomicOr(&Fl[qt], 1u << kt);
}

// ------------- Flash attention, swapped-QK 32x32 MFMA, in-register softmax -------------
// Q [B*H][S][64], K [B*KV][S][64], Vt [B*KV][64][S-permuted], Fl tile flags, Ao [B*S][2048] bf16
// 4 waves/block; each wave: 32 q rows. KV tile = 64 keys, double-buffered LDS, XOR-swizzled.
// Scores stay RAW (p = exp2(a*C - mrun2)); mask folds as a += mk*8. V fragments are single
// ds_read_b128 thanks to the permuted vT storage (keys already in P's slot order).
__global__ __launch_bounds__(256, 4) void attn(const u16* __restrict__ Q, const u16* __restrict__ Kb,
                                               const u16* __restrict__ Vt, const float* __restrict__ mask,
                                               const unsigned* __restrict__ Fl, u16* __restrict__ Ao) {
  __shared__ u16 Ks[2][4096];
  __shared__ u16 Vs[2][4096];
  __shared__ float cbuf[128];
  const int bid = blockIdx.x;
  const int qt = bid & 15, h = (bid >> 4) & 31, b = bid >> 9;
  const int kv = h >> 2;
  const int tid = threadIdx.x, w = tid >> 6, l = tid & 63;
  const int lq = l & 31, hi = l >> 5;

  const float C = 0.125f * 1.44269504088896f;  // SCL * log2(e)
  const float THR = 11.5416f;                  // 8 nats in log2 units

  // Q fragments (B-operand): lane lq = q col, d = t*16 + hi*8 + j
  const u16* Qb = Q + ((size_t)((b * 32 + h) * 2048 + qt * 128 + w * 32 + lq)) * 64;
  bf16x8 qf[4];
#pragma unroll
  for (int t = 0; t < 4; ++t)
    qf[t] = *(const bf16x8*)(Qb + t * 16 + hi * 8);

  const u16* Ksrc = Kb + (size_t)(b * 8 + kv) * 2048 * 64;
  const u16* Vsrc = Vt + (size_t)(b * 8 + kv) * 64 * 2048;
  const float* Mrow = mask + (size_t)(qt * 128 + w * 32 + lq) * 2048;
  const unsigned flagbits = Fl[qt];

  // ---- hoisted LDS byte offsets (kt-invariant) ----
  const int lx = lq & 7;
  int koff[8];   // K-frag: [ks*4+t]
#pragma unroll
  for (int ks = 0; ks < 2; ++ks)
#pragma unroll
    for (int t = 0; t < 4; ++t)
      koff[ks * 4 + t] = (lq + 32 * ks) * 128 + ((((t << 1) + hi) ^ lx) << 4);
  int voff[8];   // V-frag: [((ks*2)+t)*2+dblk]
#pragma unroll
  for (int ks = 0; ks < 2; ++ks)
#pragma unroll
    for (int t = 0; t < 2; ++t)
#pragma unroll
      for (int dblk = 0; dblk < 2; ++dblk)
        voff[(ks * 2 + t) * 2 + dblk] =
            (lq + 32 * dblk) * 128 + ((((ks << 2) + (t << 1) + hi) ^ lx) << 4);

  // ---- hoisted staging offsets ----
  size_t kgoff[2], vgoff[2];
  int ldso[2];
#pragma unroll
  for (int j = 0; j < 2; ++j) {
    int c = w * 64 + j * 256 + l;       // 16B chunk id 0..511
    int row = c >> 3;
    int sc_ = ((c & 7) ^ (row & 7)) * 8;  // pre-swizzled source chunk (elements)
    kgoff[j] = (size_t)row * 64 + sc_;
    vgoff[j] = (size_t)row * 2048 + sc_;
    ldso[j] = (w * 64 + j * 256) * 8;
  }

  f32x16 o0, o1;
#pragma unroll
  for (int i = 0; i < 16; ++i) { o0[i] = 0.f; o1[i] = 0.f; }
  float mrun2 = -3.0e38f, lrun = 0.f;

  auto stage = [&](int kt2, int bu2) {
#pragma unroll
    for (int j = 0; j < 2; ++j) {
      gload16(Ksrc + (size_t)kt2 * 4096 + kgoff[j], &Ks[bu2][ldso[j]]);
      gload16(Vsrc + (size_t)kt2 * 64 + vgoff[j], &Vs[bu2][ldso[j]]);
    }
  };

  stage(0, 0);
  __syncthreads();

  for (int kt = 0; kt < 32; ++kt) {
    const int bu = kt & 1;
    if (kt < 31) stage(kt + 1, bu ^ 1);
    const char* KL = (const char*)Ks[bu];
    const char* VL = (const char*)Vs[bu];

    // ---- QK^T swapped: raw scores a[k][q] = sum_d K[k][d] Q[q][d] ----
    f32x16 sS[2];
#pragma unroll
    for (int ks = 0; ks < 2; ++ks) {
      f32x16 a;
#pragma unroll
      for (int i = 0; i < 16; ++i) a[i] = 0.f;
      __builtin_amdgcn_s_setprio(1);
#pragma unroll
      for (int t = 0; t < 4; ++t) {
        bf16x8 kf = *(const bf16x8*)(KL + koff[ks * 4 + t]);
        a = __builtin_amdgcn_mfma_f32_32x32x16_bf16(kf, qf[t], a, 0, 0, 0);
      }
      __builtin_amdgcn_s_setprio(0);
      sS[ks] = a;
    }

    // ---- rare path: fold mask into raw scores (a += mk * 8, since raw*SCL = real) ----
    if (flagbits & (1u << kt)) {
#pragma unroll
      for (int ks = 0; ks < 2; ++ks)
#pragma unroll
        for (int g = 0; g < 4; ++g) {
          f32x4 mk = *(const f32x4*)(Mrow + kt * 64 + ks * 32 + g * 8 + hi * 4);
#pragma unroll
          for (int i = 0; i < 4; ++i) sS[ks][g * 4 + i] = fmaf(mk[i], 8.0f, sS[ks][g * 4 + i]);
        }
    }

    // ---- row max via max3 tree, then to log2 units ----
    float m0_ = max3f(sS[0][0], sS[0][1], sS[0][2]);
    float m1_ = max3f(sS[0][3], sS[0][4], sS[0][5]);
    float m2_ = max3f(sS[0][6], sS[0][7], sS[0][8]);
    float m3_ = max3f(sS[0][9], sS[0][10], sS[0][11]);
    float m4_ = max3f(sS[0][12], sS[0][13], sS[0][14]);
    float m5_ = max3f(sS[0][15], sS[1][0], sS[1][1]);
    float m6_ = max3f(sS[1][2], sS[1][3], sS[1][4]);
    float m7_ = max3f(sS[1][5], sS[1][6], sS[1][7]);
    float m8_ = max3f(sS[1][8], sS[1][9], sS[1][10]);
    float m9_ = max3f(sS[1][11], sS[1][12], sS[1][13]);
    float ma_ = fmaxf(sS[1][14], sS[1][15]);
    m0_ = max3f(m0_, m1_, m2_);
    m3_ = max3f(m3_, m4_, m5_);
    m6_ = max3f(m6_, m7_, m8_);
    m9_ = max3f(m9_, ma_, m0_);
    float tmax = max3f(m3_, m6_, m9_);
    tmax = fmaxf(tmax, __shfl_xor(tmax, 32));
    float t2 = tmax * C;

    // ---- defer-max rescale (T13) ----
    if (!__all(t2 - mrun2 <= THR)) {
      float mnew = fmaxf(mrun2, t2);
      float corr = exp2f(mrun2 - mnew);
      mrun2 = mnew;
      lrun *= corr;
      if (l < 32) cbuf[(w << 5) + l] = corr;
      asm volatile("s_waitcnt lgkmcnt(0)" ::: "memory");
#pragma unroll
      for (int r = 0; r < 16; ++r) {
        float c = cbuf[(w << 5) + ((r & 3) + 8 * (r >> 2) + 4 * hi)];
        o0[r] *= c; o1[r] *= c;
      }
    }

    // ---- p = exp2(a*C - mrun2)  (single fma + exp per score), tree sum ----
    float ps0 = 0.f, ps1 = 0.f, ps2 = 0.f, ps3 = 0.f;
#pragma unroll
    for (int ks = 0; ks < 2; ++ks)
#pragma unroll
      for (int i = 0; i < 16; i += 4) {
        float p0 = exp2f(sS[ks][i] * C - mrun2);
        float p1 = exp2f(sS[ks][i + 1] * C - mrun2);
        float p2 = exp2f(sS[ks][i + 2] * C - mrun2);
        float p3 = exp2f(sS[ks][i + 3] * C - mrun2);
        sS[ks][i] = p0; sS[ks][i + 1] = p1; sS[ks][i + 2] = p2; sS[ks][i + 3] = p3;
        ps0 += p0; ps1 += p1; ps2 += p2; ps3 += p3;
      }
    float psum = (ps0 + ps1) + (ps2 + ps3);
    psum += __shfl_xor(psum, 32);
    lrun += psum;

    // ---- P -> bf16 (lane-resident; slot j = key (j&3)+8*(j>>2)+4hi), PV via b128 V reads ----
#pragma unroll
    for (int ks = 0; ks < 2; ++ks) {
      unsigned uu0 = cvtpk(sS[ks][0], sS[ks][1]);
      unsigned uu1 = cvtpk(sS[ks][2], sS[ks][3]);
      unsigned uu2 = cvtpk(sS[ks][4], sS[ks][5]);
      unsigned uu3 = cvtpk(sS[ks][6], sS[ks][7]);
      unsigned uu4 = cvtpk(sS[ks][8], sS[ks][9]);
      unsigned uu5 = cvtpk(sS[ks][10], sS[ks][11]);
      unsigned uu6 = cvtpk(sS[ks][12], sS[ks][13]);
      unsigned uu7 = cvtpk(sS[ks][14], sS[ks][15]);
      __builtin_amdgcn_s_setprio(1);
#pragma unroll
      for (int t = 0; t < 2; ++t) {
        u32x4 wv_;
        if (t == 0) wv_ = (u32x4){uu0, uu1, uu2, uu3};
        else        wv_ = (u32x4){uu4, uu5, uu6, uu7};
        bf16x8 pa = __builtin_bit_cast(bf16x8, wv_);
#pragma unroll
        for (int dblk = 0; dblk < 2; ++dblk) {
          bf16x8 vfrag = *(const bf16x8*)(VL + voff[(ks * 2 + t) * 2 + dblk]);
          if (dblk == 0) o0 = __builtin_amdgcn_mfma_f32_32x32x16_bf16(pa, vfrag, o0, 0, 0, 0);
          else           o1 = __builtin_amdgcn_mfma_f32_32x32x16_bf16(pa, vfrag, o1, 0, 0, 0);
        }
      }
      __builtin_amdgcn_s_setprio(0);
    }

    __syncthreads();
  }

  // ---- epilogue: broadcast 1/lrun via LDS, normalize, store ----
  if (l < 32) cbuf[(w << 5) + l] = 1.0f / lrun;
  asm volatile("s_waitcnt lgkmcnt(0)" ::: "memory");
#pragma unroll
  for (int r = 0; r < 16; ++r) {
    int oq = (r & 3) + 8 * (r >> 2) + 4 * hi;
    float inv = cbuf[(w << 5) + oq];
    int srow = qt * 128 + w * 32 + oq;
    size_t tok = (size_t)(b * 2048 + srow);
    Ao[tok * 2048 + h * 64 + lq]      = f2bf(o0[r] * inv);
    Ao[tok * 2048 + h * 64 + 32 + lq] = f2bf(o1[r] * inv);
  }
}

extern "C" void kernel_launch(void* const* d_in, const int* in_sizes, int n_in,
                              void* d_out, int out_size, void* d_ws, size_t ws_size,
                              hipStream_t stream) {
  const float* x    = (const float*)d_in[0];
  const float* fcos = (const float*)d_in[1];
  const float* fsin = (const float*)d_in[2];
  const float* mask = (const float*)d_in[3];
  const float* wq   = (const float*)d_in[4];
  const float* wk   = (const float*)d_in[5];
  const float* wv   = (const float*)d_in[6];
  const float* wo   = (const float*)d_in[7];
  float* out = (float*)d_out;

  // workspace layout (u16 elements), total ~79.7 MB
  u16* ws  = (u16*)d_ws;
  u16* xb  = ws;                       // 8,388,608   x bf16; later reused as attn_out
  u16* wT  = ws + 8388608;             // 6,291,456   wqkvT [3072][2048]; later woT [2048][2048]
  u16* qkv = ws + 14680064;            // 12,582,912  qkv [4096][3072]; first 64B reused as mask flags
  u16* qb  = ws + 27262976;            // 8,388,608   Q [B][32][S][64]
  u16* kb  = ws + 35651584;            // 2,097,152   K [B][8][S][64]
  u16* vT  = ws + 37748736;            // 2,097,152   V^T [B*8][64][S] (token cols permuted)
  unsigned* Fl = (unsigned*)qkv;       // 16 u32 (qkv is dead by the time flags are written)

  cvt_x<<<8192, 256, 0, stream>>>(x, xb);
  transpose_cvt<<<dim3(64, 64), dim3(32, 8), 0, stream>>>(wq, wT, 2048, 2048);
  transpose_cvt<<<dim3(16, 64), dim3(32, 8), 0, stream>>>(wk, wT + (size_t)2048 * 2048, 2048, 512);
  transpose_cvt<<<dim3(16, 64), dim3(32, 8), 0, stream>>>(wv, wT + (size_t)2560 * 2048, 2048, 512);
  gemm_bt<1><<<dim3(24, 32), 256, 0, stream>>>(xb, wT, qkv, 4096, 3072, 2048);
  transpose_cvt<<<dim3(64, 64), dim3(32, 8), 0, stream>>>(wo, wT, 2048, 2048);  // after gemm1 (wT reuse)
  rope_kernel<<<16384, 256, 0, stream>>>(qkv, fcos, fsin, qb, 5, 0);
  rope_kernel<<<4096, 256, 0, stream>>>(qkv, fcos, fsin, kb, 3, 2048);
  vtrans<<<dim3(16, 128), dim3(32, 8), 0, stream>>>(qkv, vT);
  hipMemsetAsync(Fl, 0, 16 * sizeof(unsigned), stream);   // qkv fully consumed above
  mask_flags<<<dim3(16, 32), 256, 0, stream>>>(mask, Fl);
  attn<<<1024, 256, 0, stream>>>(qb, kb, vT, mask, Fl, xb);
  gemm_bt<0><<<dim3(16, 32), 256, 0, stream>>>(xb, wT, out, 4096, 2048, 2048);
}